// Round 19
// baseline (171.616 us; speedup 1.0000x reference)
//
#include <hip/hip_runtime.h>
#include <hip/hip_bf16.h>

#define NTOK 512
#define TJ 32
#define NHALF 8            // j-tiles per half (waves 0-7: j<256, waves 8-15: j>=256)
#define EPSF 1e-5f

typedef __attribute__((ext_vector_type(4))) float f32x4;
typedef __attribute__((ext_vector_type(8))) short bf16x8;
typedef __attribute__((ext_vector_type(4))) short bf16x4;

struct HL { short hi; short lo; };

__device__ __forceinline__ short f2bf(float x) {
  __hip_bfloat16 h = __float2bfloat16(x);
  return *reinterpret_cast<short*>(&h);
}
__device__ __forceinline__ float bf2f(short s) {
  unsigned int u = ((unsigned int)(unsigned short)s) << 16;
  return __uint_as_float(u);
}
// RNE split x ~= hi + lo (~17 mantissa bits combined)
__device__ __forceinline__ HL splitbf(float x) {
  HL r;
  r.hi = f2bf(x);
  r.lo = f2bf(x - bf2f(r.hi));
  return r;
}

// Per-half SINGLE-BUFFERED main-loop LDS (31872 B each) + block-shared split
// WA weights (8192 B). Total 71936 B/block -> TWO 1024-thread blocks fit in
// 160 KB/CU (143872 <= 163840).
struct __align__(16) SMemHalf {
  float f0s[32*17];      // [j][f], stride 17
  float f1s[32*48];      // [j][c*3+x], stride 48 (unpadded, linear-writable)
  float rhs[96];         // [j*3+x]
  float maskf[32];
  short rbfHL[32*40];    // [j][k]: k<16 hi, k>=16 lo; 80B row stride
  short Hh[128*40];      // [h][j] bf16 hi, stride 40
  short Hl[128*40];      // lo
};
union __align__(16) SMemU {
  struct {
    SMemHalf h[2];       // 63744 B
    short wah[128*16];   // split WA hi, staged once in prologue (shared, 4 KB)
    short wal[128*16];   // split WA lo (4 KB)
  } m;
  struct {               // epilogue region (disjoint lifetime; ~22 KB)
    float ACCs[128*33];
    float biasR[128];
    float part[1024];
    float m00s[16], m10s[16], p01s[48], p11s[48], rawbs[48], nrms[16];
  } e;
};

// R18's measured structure (63.0 us steady / 168.7 bench best) with ONE
// change: WA B-frags (bw1/bw2 = 8 VGPRs live kernel-wide) moved to LDS,
// re-read per tile as two short-lived ds_read_b128. Goal: arch VGPR <= 56 so
// total (arch + 8 acc) <= 64 = 8-waves/SIMD boundary -> 2 blocks/CU -> 2x TLP
// (the remaining big lever: occupancy 40% -> ~80%). R17 cut 75->64 via
// streamed LHS but landed at 60 arch; this removes the next 8.
// Fallback is neutral: if allocator stays 57-60, cost = 2 LDS reads/tile.
// Locked-in: NEVER launch_bounds(x,8) (R3/R11: forced 32-reg + 260-660 MB
// scratch); no __threadfence rendezvous (R9: ~380 us).
__global__ __launch_bounds__(1024, 4) void tfn_kernel(
    const float* __restrict__ f0,  const float* __restrict__ f1,
    const float* __restrict__ rbf, const float* __restrict__ rhat,
    const int*  __restrict__ mask,
    const float* __restrict__ w00a, const float* __restrict__ b00a,
    const float* __restrict__ w00b, const float* __restrict__ b00b,
    const float* __restrict__ w10a, const float* __restrict__ b10a,
    const float* __restrict__ w10b, const float* __restrict__ b10b,
    const float* __restrict__ w01a, const float* __restrict__ b01a,
    const float* __restrict__ w01b, const float* __restrict__ b01b,
    const float* __restrict__ w11a, const float* __restrict__ b11a,
    const float* __restrict__ w11b, const float* __restrict__ b11b,
    const float* __restrict__ g0, const float* __restrict__ be0,
    const float* __restrict__ g1, const float* __restrict__ be1,
    float* __restrict__ out)
{
  __shared__ SMemU sm;
  const int i = blockIdx.x;
  const int t = threadIdx.x;          // 0..1023
  const int half = t >> 9;            // j-half this thread works on
  const int th = t & 511;             // thread id within half
  const int w8 = th >> 6;             // wave id within half, 0..7
  const int lane = t & 63;
  const int col = lane & 15;
  const int quad = lane >> 4;
  const int jbase = half * (NHALF * TJ);
  SMemHalf* smh = &sm.m.h[half];

  // ---- cooperative WA split staging (2048 entries / 1024 threads = 2 each) ----
  {
    #pragma unroll
    for (int rep = 0; rep < 2; ++rep) {
      const int idx = t + rep*1024;
      const int hh = idx >> 4, kk = idx & 15;
      const float* wrow = (hh < 32) ? (w00a + hh*16) : (hh < 64) ? (w10a + (hh-32)*16)
                        : (hh < 96) ? (w01a + (hh-64)*16) : (w11a + (hh-96)*16);
      HL s = splitbf(wrow[kk]);
      sm.m.wah[idx] = s.hi;
      sm.m.wal[idx] = s.lo;
    }
  }

  // ---- per-wave bias (1 scalar) ----
  float bav;
  {
    const int h = w8*16 + col;
    bav = (w8 < 2) ? b00a[h] : (w8 < 4) ? b10a[h-32] : (w8 < 6) ? b01a[h-64] : b11a[h-96];
  }

  // ---- per-lane LHS constants (wave-uniform branch selectors) ----
  int fdiv = 0, xrem = 0, cidx = 0;
  if (w8 >= 2 && w8 < 5) { const int idx = (w8-2)*16 + col; fdiv = idx/3; xrem = idx - 3*fdiv; }
  if (w8 >= 5) cidx = (w8-5)*16 + col;
  const int hb = (w8 == 0) ? 0 : (w8 == 1) ? 2 : (w8 < 5) ? 4 : 6;

  const int jrow = th >> 4, jfeat = th & 15;   // f0/rbf staging coords
  const int hrow = w8*16 + col;                // this lane's WA row

  // ---- prefetch tile 0 of this half ----
  float pf_f0, pf_f1_0, pf_f1_1, pf_f1_2, pf_rh = 0.f, pf_rbf;
  int pf_mk = 0;
  {
    pf_f0   = f0[(jbase + jrow)*16 + jfeat];
    pf_f1_0 = f1[jbase*48 + th]; pf_f1_1 = f1[jbase*48 + th + 512]; pf_f1_2 = f1[jbase*48 + th + 1024];
    if (th < 96) pf_rh = rhat[((size_t)i*NTOK + jbase)*3 + th];
    if (th < 32) pf_mk = mask[(size_t)i*NTOK + jbase + th];
    pf_rbf  = rbf[((size_t)i*NTOK + jbase + jrow)*16 + jfeat];
  }

  f32x4 acc0 = {0.f,0.f,0.f,0.f}, acc1 = {0.f,0.f,0.f,0.f};
  float biasp = 0.f;
  const f32x4 zc = {0.f,0.f,0.f,0.f};
  const bf16x8 zb = {0,0,0,0,0,0,0,0};

  for (int tile = 0; tile < NHALF; ++tile) {
    // ---- stage regs -> this half's LDS (f1: linear, index-register-free) ----
    smh->f0s[jrow*17 + jfeat] = pf_f0;
    smh->f1s[th]        = pf_f1_0;
    smh->f1s[th + 512]  = pf_f1_1;
    smh->f1s[th + 1024] = pf_f1_2;
    if (th < 96) smh->rhs[th] = pf_rh;
    if (th < 32) smh->maskf[th] = pf_mk ? 1.f : 0.f;
    { HL s = splitbf(pf_rbf);
      smh->rbfHL[jrow*40 + jfeat]      = s.hi;
      smh->rbfHL[jrow*40 + 16 + jfeat] = s.lo; }
    __syncthreads();   // staging (and prologue WA on tile 0) visible

    // ---- prefetch tile+1 ----
    if (tile + 1 < NHALF) {
      const int j0 = jbase + (tile+1)*TJ;
      pf_f0   = f0[(j0 + jrow)*16 + jfeat];
      pf_f1_0 = f1[j0*48 + th]; pf_f1_1 = f1[j0*48 + th + 512]; pf_f1_2 = f1[j0*48 + th + 1024];
      if (th < 96) pf_rh = rhat[((size_t)i*NTOK + j0)*3 + th];
      if (th < 32) pf_mk = mask[(size_t)i*NTOK + j0 + th];
      pf_rbf  = rbf[((size_t)i*NTOK + j0 + jrow)*16 + jfeat];
    }

    // ---- phase A: H = silu(rbf @ WA^T + ba); WA frags read from LDS ----
    {
      const bf16x8 bw1 = *(const bf16x8*)&sm.m.wah[hrow*16 + (quad & 1)*8];
      const bf16x8 bw2 = (quad < 2) ? *(const bf16x8*)&sm.m.wal[hrow*16 + quad*8] : zb;
      const bf16x8 a0 = *(const bf16x8*)&smh->rbfHL[col*40 + quad*8];
      const bf16x8 a1 = *(const bf16x8*)&smh->rbfHL[(16+col)*40 + quad*8];
      f32x4 d0 = __builtin_amdgcn_mfma_f32_16x16x32_bf16(a0, bw1, zc, 0, 0, 0);
      d0 = __builtin_amdgcn_mfma_f32_16x16x32_bf16(a0, bw2, d0, 0, 0, 0);
      f32x4 d1 = __builtin_amdgcn_mfma_f32_16x16x32_bf16(a1, bw1, zc, 0, 0, 0);
      d1 = __builtin_amdgcn_mfma_f32_16x16x32_bf16(a1, bw2, d1, 0, 0, 0);
      bf16x4 hv, lv;
      #pragma unroll
      for (int r = 0; r < 4; ++r) {
        float p = d0[r] + bav;
        float s = p * __builtin_amdgcn_rcpf(1.f + __expf(-p));
        HL e2 = splitbf(s); hv[r] = e2.hi; lv[r] = e2.lo;
      }
      *(bf16x4*)&smh->Hh[(w8*16+col)*40 + quad*4] = hv;
      *(bf16x4*)&smh->Hl[(w8*16+col)*40 + quad*4] = lv;
      #pragma unroll
      for (int r = 0; r < 4; ++r) {
        float p = d1[r] + bav;
        float s = p * __builtin_amdgcn_rcpf(1.f + __expf(-p));
        HL e2 = splitbf(s); hv[r] = e2.hi; lv[r] = e2.lo;
      }
      *(bf16x4*)&smh->Hh[(w8*16+col)*40 + 16 + quad*4] = hv;
      *(bf16x4*)&smh->Hl[(w8*16+col)*40 + 16 + quad*4] = lv;
    }

    // ---- LHS: STREAMED per-lane phase-B A-frag (R18-verbatim) ----
    bf16x8 afh, afl;
    {
      const int jb = quad*8;
      #pragma unroll
      for (int jj = 0; jj < 8; ++jj) {
        const int j = jb + jj;
        const float mk = smh->maskf[j];
        float v;
        if (w8 == 0) {
          v = mk * smh->f0s[j*17 + col];
        } else if (w8 == 1) {
          const float* rp = &smh->rhs[j*3];
          const float* fr = &smh->f1s[j*48 + col*3];
          v = mk * (rp[0]*fr[0] + rp[1]*fr[1] + rp[2]*fr[2]);
        } else if (w8 < 5) {
          v = mk * smh->f0s[j*17 + fdiv] * smh->rhs[j*3 + xrem];
        } else {
          v = mk * smh->f1s[j*48 + cidx];
        }
        biasp += v;
        HL s = splitbf(v);
        afh[jj] = s.hi; afl[jj] = s.lo;
      }
    }
    __syncthreads();   // H visible; staging fully consumed

    // ---- phase B: ACC += L^T * H ----
    {
      const bf16x8 b0h = *(const bf16x8*)&smh->Hh[(hb*16+col)*40 + quad*8];
      const bf16x8 b0l = *(const bf16x8*)&smh->Hl[(hb*16+col)*40 + quad*8];
      const bf16x8 b1h = *(const bf16x8*)&smh->Hh[((hb+1)*16+col)*40 + quad*8];
      const bf16x8 b1l = *(const bf16x8*)&smh->Hl[((hb+1)*16+col)*40 + quad*8];
      acc0 = __builtin_amdgcn_mfma_f32_16x16x32_bf16(afl, b0h, acc0, 0, 0, 0);
      acc0 = __builtin_amdgcn_mfma_f32_16x16x32_bf16(afh, b0l, acc0, 0, 0, 0);
      acc0 = __builtin_amdgcn_mfma_f32_16x16x32_bf16(afh, b0h, acc0, 0, 0, 0);
      acc1 = __builtin_amdgcn_mfma_f32_16x16x32_bf16(afl, b1h, acc1, 0, 0, 0);
      acc1 = __builtin_amdgcn_mfma_f32_16x16x32_bf16(afh, b1l, acc1, 0, 0, 0);
      acc1 = __builtin_amdgcn_mfma_f32_16x16x32_bf16(afh, b1h, acc1, 0, 0, 0);
    }
  }

  __syncthreads();   // all main-loop LDS reads done -> union region reusable

  // ---- merge halves: half 0 writes, half 1 accumulates ----
  biasp += __shfl_xor(biasp, 16);
  biasp += __shfl_xor(biasp, 32);
  if (half == 0) {
    #pragma unroll
    for (int r = 0; r < 4; ++r) {
      sm.e.ACCs[(w8*16 + quad*4 + r)*33 + col]      = acc0[r];
      sm.e.ACCs[(w8*16 + quad*4 + r)*33 + 16 + col] = acc1[r];
    }
    if (lane < 16) sm.e.biasR[w8*16 + col] = biasp;
  }
  __syncthreads();
  if (half == 1) {
    #pragma unroll
    for (int r = 0; r < 4; ++r) {
      sm.e.ACCs[(w8*16 + quad*4 + r)*33 + col]      += acc0[r];
      sm.e.ACCs[(w8*16 + quad*4 + r)*33 + 16 + col] += acc1[r];
    }
    if (lane < 16) sm.e.biasR[w8*16 + col] += biasp;
  }
  __syncthreads();

  // ---- epilogue: second-layer contraction, 8-way split of the 16-long d loop ----
  {
    const int tt = t & 127, oct = t >> 7;   // oct 0..7
    float s = 0.f;
    if (tt < 16) {
      const int o = tt;
      #pragma unroll
      for (int dd = 0; dd < 2; ++dd) {
        const int d = oct + dd*8;
        const float* wrow = w00b + (d*16 + o)*32;
        float ss = 0.f;
        #pragma unroll
        for (int hh = 0; hh < 32; ++hh) ss += wrow[hh] * sm.e.ACCs[d*33 + hh];
        s += ss + b00b[d*16 + o] * sm.e.biasR[d];
      }
    } else if (tt < 32) {
      const int o = tt - 16;
      #pragma unroll
      for (int dd = 0; dd < 2; ++dd) {
        const int c = oct + dd*8, m = 16 + c;
        const float* wrow = w10b + (c*16 + o)*32;
        float ss = 0.f;
        #pragma unroll
        for (int hh = 0; hh < 32; ++hh) ss += wrow[hh] * sm.e.ACCs[m*33 + hh];
        s += ss + b10b[c*16 + o] * sm.e.biasR[m];
      }
    } else if (tt < 80) {
      const int idx = tt - 32, g = idx/3, x = idx - 3*g;
      #pragma unroll
      for (int dd = 0; dd < 2; ++dd) {
        const int f = oct + dd*8, m = 32 + f*3 + x;
        const float* wrow = w01b + (f*16 + g)*32;
        float ss = 0.f;
        #pragma unroll
        for (int hh = 0; hh < 32; ++hh) ss += wrow[hh] * sm.e.ACCs[m*33 + hh];
        s += ss + b01b[f*16 + g] * sm.e.biasR[m];
      }
    } else {
      const int idx = tt - 80, g = idx/3, x = idx - 3*g;
      #pragma unroll
      for (int dd = 0; dd < 2; ++dd) {
        const int k = oct + dd*8, m = 80 + k*3 + x;
        const float* wrow = w11b + (k*16 + g)*32;
        float ss = 0.f;
        #pragma unroll
        for (int hh = 0; hh < 32; ++hh) ss += wrow[hh] * sm.e.ACCs[m*33 + hh];
        s += ss + b11b[k*16 + g] * sm.e.biasR[m];
      }
    }
    sm.e.part[t] = s;
  }
  __syncthreads();

  if (t < 128) {
    float s = 0.f;
    #pragma unroll
    for (int k = 0; k < 8; ++k) s += sm.e.part[t + 128*k];
    if (t < 16) sm.e.m00s[t] = s;
    else if (t < 32) sm.e.m10s[t-16] = s;
    else if (t < 80) sm.e.p01s[t-32] = s;
    else sm.e.p11s[t-80] = s;
  }
  __syncthreads();

  if (t < 16) {
    float vv = sm.e.m00s[t] + sm.e.m10s[t];
    float mu = 0.f;
    #pragma unroll
    for (int k = 0; k < 16; ++k) mu += sm.e.m00s[k] + sm.e.m10s[k];
    mu *= (1.f/16.f);
    float var = 0.f;
    #pragma unroll
    for (int k = 0; k < 16; ++k) { float d = sm.e.m00s[k] + sm.e.m10s[k] - mu; var += d*d; }
    var *= (1.f/16.f);
    out[(size_t)i*16 + t] = (vv - mu) * rsqrtf(var + EPSF) * g0[t] + be0[t];
    float r0v = sm.e.p01s[t*3+0] + sm.e.p11s[t*3+0];
    float r1v = sm.e.p01s[t*3+1] + sm.e.p11s[t*3+1];
    float r2v = sm.e.p01s[t*3+2] + sm.e.p11s[t*3+2];
    sm.e.rawbs[t*3+0] = r0v; sm.e.rawbs[t*3+1] = r1v; sm.e.rawbs[t*3+2] = r2v;
    sm.e.nrms[t] = fmaxf(sqrtf(r0v*r0v + r1v*r1v + r2v*r2v), 1e-8f);
  }
  __syncthreads();
  if (t < 16) {
    float mu = 0.f;
    #pragma unroll
    for (int k = 0; k < 16; ++k) mu += sm.e.nrms[k];
    mu *= (1.f/16.f);
    float var = 0.f;
    #pragma unroll
    for (int k = 0; k < 16; ++k) { float d = sm.e.nrms[k] - mu; var += d*d; }
    var *= (1.f/16.f);
    const float ln = (sm.e.nrms[t] - mu) * rsqrtf(var + EPSF) * g1[t] + be1[t];
    const float scale = ln / sm.e.nrms[t];
    const size_t base = (size_t)NTOK*16 + (size_t)i*48 + t*3;
    out[base+0] = sm.e.rawbs[t*3+0] * scale;
    out[base+1] = sm.e.rawbs[t*3+1] * scale;
    out[base+2] = sm.e.rawbs[t*3+2] * scale;
  }
}

extern "C" void kernel_launch(void* const* d_in, const int* in_sizes, int n_in,
                              void* d_out, int out_size, void* d_ws, size_t ws_size,
                              hipStream_t stream) {
  int idx_f0 = -1, idx_f1 = -1, idx_rbf = -1, idx_rhat = -1, idx_mask = -1;
  int wa_i[4], ba_i[4], wb_i[4], bb_i[4], g_i[4];
  int nwa = 0, nba = 0, nwb = 0, nbb = 0, ng = 0;
  for (int k = 0; k < n_in; ++k) {
    const int s = in_sizes[k];
    if      (s == 4194304) idx_rbf  = k;
    else if (s == 786432)  idx_rhat = k;
    else if (s == 262144)  idx_mask = k;
    else if (s == 24576)   idx_f1   = k;
    else if (s == 8192)    { if (idx_f0 < 0) idx_f0 = k; else if (nwb < 4) wb_i[nwb++] = k; }
    else if (s == 512)     { if (nwa < 4) wa_i[nwa++] = k; }
    else if (s == 32)      { if (nba < 4) ba_i[nba++] = k; }
    else if (s == 256)     { if (nbb < 4) bb_i[nbb++] = k; }
    else if (s == 16)      { if (ng  < 4) g_i[ng++]  = k; }
  }
  const bool ok = idx_f0 >= 0 && idx_f1 >= 0 && idx_rbf >= 0 && idx_rhat >= 0 &&
                  idx_mask >= 0 && nwa == 4 && nba == 4 && nwb == 4 && nbb == 4 && ng == 4;
  if (!ok) {
    idx_f0 = 1; idx_f1 = 2; idx_rbf = 3; idx_rhat = 4; idx_mask = 5;
    for (int q = 0; q < 4; ++q) {
      wa_i[q] = 6 + q*4; ba_i[q] = 7 + q*4; wb_i[q] = 8 + q*4; bb_i[q] = 9 + q*4;
      g_i[q] = 22 + q;
    }
  }
  tfn_kernel<<<512, 1024, 0, stream>>>(
      (const float*)d_in[idx_f0],  (const float*)d_in[idx_f1],
      (const float*)d_in[idx_rbf], (const float*)d_in[idx_rhat],
      (const int*)d_in[idx_mask],
      (const float*)d_in[wa_i[0]], (const float*)d_in[ba_i[0]],
      (const float*)d_in[wb_i[0]], (const float*)d_in[bb_i[0]],
      (const float*)d_in[wa_i[1]], (const float*)d_in[ba_i[1]],
      (const float*)d_in[wb_i[1]], (const float*)d_in[bb_i[1]],
      (const float*)d_in[wa_i[2]], (const float*)d_in[ba_i[2]],
      (const float*)d_in[wb_i[2]], (const float*)d_in[bb_i[2]],
      (const float*)d_in[wa_i[3]], (const float*)d_in[ba_i[3]],
      (const float*)d_in[wb_i[3]], (const float*)d_in[bb_i[3]],
      (const float*)d_in[g_i[0]], (const float*)d_in[g_i[1]],
      (const float*)d_in[g_i[2]], (const float*)d_in[g_i[3]],
      (float*)d_out);
}